// Round 1
// 793.843 us; speedup vs baseline: 1.2005x; 1.2005x over previous
//
#include <hip/hip_runtime.h>

// MixedScaleDenseLayer: out[n, 0:32]  = x
//                       out[n, 32+j]  = bias[j] + sum_c conv3x3_dilated(x[n,c], W[j,c], d=j+1)
// x: [8,32,512,512] f32, W: [10,32,3,3] f32, b: [10] f32, out: [8,42,512,512] f32
//
// Strategy: 16x128 output tile per 256-thread block. Channels processed in
// pairs packed as half2 in LDS (halves LDS bytes); v_dot2_f32_f16 does 2 MACs
// per instr with f32 accumulate. Thread owns 8 consecutive w pixels x 10
// dilations (80 f32 accums). LDS layout swizzled p(wl)=(wl&7)*19+(wl>>3) so the
// stride-8 thread ownership reads consecutive banks (2-way conflict = free).
// x-copy to out channels is fused from the center-row values already loaded.
//
// __launch_bounds__(256, 4): cap VGPRs at 128 so 4 blocks/CU are resident
// (was 136 VGPR -> 3 blocks/CU -> 11.9% occupancy + 33% grid tail; grid is
// exactly 1024 = 256 CU x 4 so 4-resident means zero tail). Kernel is
// latency-bound (VALU 19%, HBM 13.6%, LDS ~40%), so +33% waves is the lever.

#define TH   16
#define TW   128
#define HALO 10
#define PADW 12
#define SH   (TH + 2 * HALO)   // 36 staged rows
#define SW   (TW + 2 * PADW)   // 152 staged cols (also LDS row stride)
#define NCP  16                // channel pairs
#define ND   10                // dilations
#define IMG  512

// __fp16 (not _Float16): matches clang's __builtin_amdgcn_{fdot2,cvt_pkrtz}
// signatures ("V2h" = vector of 2 __fp16).
typedef __fp16 half2v __attribute__((ext_vector_type(2)));

#if defined(__has_builtin)
#  if __has_builtin(__builtin_amdgcn_fdot2)
#    define HAVE_FDOT2 1
#  endif
#endif

__device__ __forceinline__ float dot2f(half2v a, half2v w, float c) {
#ifdef HAVE_FDOT2
  return __builtin_amdgcn_fdot2(a, w, c, false);
#else
  return c + (float)a[0] * (float)w[0] + (float)a[1] * (float)w[1];
#endif
}

__device__ __forceinline__ half2v pack2(float a, float b) {
#if defined(__has_builtin) && __has_builtin(__builtin_amdgcn_cvt_pkrtz)
  return __builtin_amdgcn_cvt_pkrtz(a, b);
#else
  half2v r; r[0] = (__fp16)a; r[1] = (__fp16)b; return r;
#endif
}

// swizzled position within a staged row: bijection [0,152) -> [0,152)
#define SWIZ(wl) ((((wl) & 7) * 19) + ((wl) >> 3))

__global__ __launch_bounds__(256, 4)
void msd_kernel(const float* __restrict__ x, const float* __restrict__ W,
                const float* __restrict__ b, float* __restrict__ out) {
  __shared__ half2v tile[SH * SW];     // 21888 B
  __shared__ half2v wlds[NCP * 90];    //  5760 B

  const int tid = threadIdx.x;
  const int h0  = blockIdx.x * TH;   // h-tiles fastest: h-halo L2 locality
  const int w0  = blockIdx.y * TW;
  const int n   = blockIdx.z;

  // stage packed per-channel-pair weights: wlds[cp*90 + j*9 + kh*3 + kw]
  for (int s = tid; s < NCP * 90; s += 256) {
    int cp = s / 90;
    int r  = s - cp * 90;          // j*9 + kh*3 + kw
    int j  = r / 9;
    int t9 = r - j * 9;
    float wa = W[(j * 32 + 2 * cp) * 9 + t9];
    float wb = W[(j * 32 + 2 * cp + 1) * 9 + t9];
    wlds[s] = pack2(wa, wb);
  }

  const int row = tid >> 4;          // 0..15 (output row within tile)
  const int wi  = tid & 15;          // 0..15 (8-pixel chunk within tile)
  const int h   = h0 + row;
  const int wb_ = w0 + wi * 8;

  float acc[ND][8];
  #pragma unroll
  for (int d = 0; d < ND; ++d) {
    float bv = b[d];
    #pragma unroll
    for (int j = 0; j < 8; ++j) acc[d][j] = bv;
  }

  for (int cp = 0; cp < NCP; ++cp) {
    __syncthreads();   // previous iter's readers done (also covers wlds, iter 0)
    {
      const float* xa  = x + (((size_t)n * 32 + 2 * cp) * IMG) * IMG;
      const float* xbp = xa + (size_t)IMG * IMG;
      for (int s = tid; s < SH * (SW / 4); s += 256) {   // 1368 float4 slots
        int r  = s / (SW / 4);
        int q  = s - r * (SW / 4);
        int gh = h0 - HALO + r;
        int gw = w0 - PADW + 4 * q;
        float va[4] = {0.f, 0.f, 0.f, 0.f};
        float vb[4] = {0.f, 0.f, 0.f, 0.f};
        if ((unsigned)gh < (unsigned)IMG) {
          const float* pa = xa  + (size_t)gh * IMG;
          const float* pb = xbp + (size_t)gh * IMG;
          if (gw >= 0 && gw + 3 < IMG) {
            float4 t0 = *(const float4*)(pa + gw);
            float4 t1 = *(const float4*)(pb + gw);
            va[0] = t0.x; va[1] = t0.y; va[2] = t0.z; va[3] = t0.w;
            vb[0] = t1.x; vb[1] = t1.y; vb[2] = t1.z; vb[3] = t1.w;
          } else {
            #pragma unroll
            for (int i = 0; i < 4; ++i) {
              int c = gw + i;
              if ((unsigned)c < (unsigned)IMG) { va[i] = pa[c]; vb[i] = pb[c]; }
            }
          }
        }
        int rb = r * SW;
        #pragma unroll
        for (int i = 0; i < 4; ++i) {
          int wl = 4 * q + i;
          tile[rb + SWIZ(wl)] = pack2(va[i], vb[i]);
        }
      }
    }
    __syncthreads();

    const half2v* wp = &wlds[cp * 90];

    // ---- center row (kh = 1) + fused x-copy ----
    {
      const half2v* trow = &tile[(row + HALO) * SW + wi];
      half2v dk[28];                       // wloc = 8*wi + 2 + k; tap k = 10+j+kw*d
      #pragma unroll
      for (int k = 0; k < 28; ++k) dk[k] = trow[SWIZ(k + 2)];

      // copy-out: x value at (h, wb_+j) is dk[10+j]
      float* o0 = out + (((size_t)n * 42 + 2 * cp) * IMG + h) * IMG + wb_;
      float* o1 = o0 + (size_t)IMG * IMG;
      *(float4*)o0       = make_float4((float)dk[10][0], (float)dk[11][0], (float)dk[12][0], (float)dk[13][0]);
      *(float4*)(o0 + 4) = make_float4((float)dk[14][0], (float)dk[15][0], (float)dk[16][0], (float)dk[17][0]);
      *(float4*)o1       = make_float4((float)dk[10][1], (float)dk[11][1], (float)dk[12][1], (float)dk[13][1]);
      *(float4*)(o1 + 4) = make_float4((float)dk[14][1], (float)dk[15][1], (float)dk[16][1], (float)dk[17][1]);

      #pragma unroll
      for (int d = 1; d <= ND; ++d) {
        half2v wv0 = wp[(d - 1) * 9 + 3];
        half2v wv1 = wp[(d - 1) * 9 + 4];
        half2v wv2 = wp[(d - 1) * 9 + 5];
        #pragma unroll
        for (int j = 0; j < 8; ++j) {
          float a0 = acc[d - 1][j];
          a0 = dot2f(dk[10 + j - d], wv0, a0);
          a0 = dot2f(dk[10 + j],     wv1, a0);
          a0 = dot2f(dk[10 + j + d], wv2, a0);
          acc[d - 1][j] = a0;
        }
      }
    }

    // ---- side rows: row offset -d -> kh=0, +d -> kh=2 ----
    #pragma unroll
    for (int d = 1; d <= ND; ++d) {
      #pragma unroll
      for (int sgn = 0; sgn < 2; ++sgn) {
        const int tr = row + HALO + (sgn ? d : -d);
        const int kh = sgn ? 2 : 0;
        const half2v* trow = &tile[tr * SW + wi];
        half2v dk[28];
        #pragma unroll
        for (int k = 10 - d; k <= 17 + d; ++k) dk[k] = trow[SWIZ(k + 2)];
        half2v wv0 = wp[(d - 1) * 9 + kh * 3 + 0];
        half2v wv1 = wp[(d - 1) * 9 + kh * 3 + 1];
        half2v wv2 = wp[(d - 1) * 9 + kh * 3 + 2];
        #pragma unroll
        for (int j = 0; j < 8; ++j) {
          float a0 = acc[d - 1][j];
          a0 = dot2f(dk[10 + j - d], wv0, a0);
          a0 = dot2f(dk[10 + j],     wv1, a0);
          a0 = dot2f(dk[10 + j + d], wv2, a0);
          acc[d - 1][j] = a0;
        }
      }
    }
  }

  // store conv outputs (channels 32..41)
  #pragma unroll
  for (int d = 0; d < ND; ++d) {
    float* op = out + (((size_t)n * 42 + 32 + d) * IMG + h) * IMG + wb_;
    *(float4*)op       = make_float4(acc[d][0], acc[d][1], acc[d][2], acc[d][3]);
    *(float4*)(op + 4) = make_float4(acc[d][4], acc[d][5], acc[d][6], acc[d][7]);
  }
}

extern "C" void kernel_launch(void* const* d_in, const int* in_sizes, int n_in,
                              void* d_out, int out_size, void* d_ws, size_t ws_size,
                              hipStream_t stream) {
  const float* x = (const float*)d_in[0];
  const float* W = (const float*)d_in[1];
  const float* b = (const float*)d_in[2];
  float* out = (float*)d_out;
  (void)in_sizes; (void)n_in; (void)out_size; (void)d_ws; (void)ws_size;
  dim3 grid(IMG / TH, IMG / TW, 8);   // (32, 4, 8)
  dim3 block(256);
  hipLaunchKernelGGL(msd_kernel, grid, block, 0, stream, x, W, b, out);
}

// Round 2
// 779.652 us; speedup vs baseline: 1.2223x; 1.0182x over previous
//
#include <hip/hip_runtime.h>

// MixedScaleDenseLayer: out[n, 0:32]  = x
//                       out[n, 32+j]  = bias[j] + sum_c conv3x3_dilated(x[n,c], W[j,c], d=j+1)
// x: [8,32,512,512] f32, W: [10,32,3,3] f32, b: [10] f32, out: [8,42,512,512] f32
//
// Strategy: 16x128 output tile per 256-thread block. Channels processed in
// pairs packed as half2 in LDS (halves LDS bytes); v_dot2_f32_f16 does 2 MACs
// per instr with f32 accumulate. Thread owns 8 consecutive w pixels x 10
// dilations (80 f32 accums). LDS layout swizzled p(wl)=(wl&7)*19+(wl>>3) so the
// stride-8 thread ownership reads consecutive banks (2-way conflict = free).
// x-copy to out channels is fused from the center-row values already loaded.
//
// Occupancy pinning history:
//   - no bounds: 136 VGPR -> 3 blocks/CU, 11.9% occ, 595 us
//   - __launch_bounds__(256,4): min-waves hint only; allocator overshot to
//     64 VGPR / 8 waves and SPILLED ~70 regs of live state (hbm_bytes
//     0.65 -> 1.27 GB of scratch traffic). 436 us despite the spills.
//   - now: amdgpu_waves_per_eu(4,4) pins min=max=4 waves/SIMD -> 128-VGPR
//     budget, which fits the 80-acc + 28-dk live set without spilling.
//     Grid 1024 = 256 CU x 4 blocks -> fully co-resident, zero tail.

#define TH   16
#define TW   128
#define HALO 10
#define PADW 12
#define SH   (TH + 2 * HALO)   // 36 staged rows
#define SW   (TW + 2 * PADW)   // 152 staged cols (also LDS row stride)
#define NCP  16                // channel pairs
#define ND   10                // dilations
#define IMG  512

// __fp16 (not _Float16): matches clang's __builtin_amdgcn_{fdot2,cvt_pkrtz}
// signatures ("V2h" = vector of 2 __fp16).
typedef __fp16 half2v __attribute__((ext_vector_type(2)));

#if defined(__has_builtin)
#  if __has_builtin(__builtin_amdgcn_fdot2)
#    define HAVE_FDOT2 1
#  endif
#endif

__device__ __forceinline__ float dot2f(half2v a, half2v w, float c) {
#ifdef HAVE_FDOT2
  return __builtin_amdgcn_fdot2(a, w, c, false);
#else
  return c + (float)a[0] * (float)w[0] + (float)a[1] * (float)w[1];
#endif
}

__device__ __forceinline__ half2v pack2(float a, float b) {
#if defined(__has_builtin) && __has_builtin(__builtin_amdgcn_cvt_pkrtz)
  return __builtin_amdgcn_cvt_pkrtz(a, b);
#else
  half2v r; r[0] = (__fp16)a; r[1] = (__fp16)b; return r;
#endif
}

// swizzled position within a staged row: bijection [0,152) -> [0,152)
#define SWIZ(wl) ((((wl) & 7) * 19) + ((wl) >> 3))

__global__ __launch_bounds__(256)
__attribute__((amdgpu_waves_per_eu(4, 4)))
void msd_kernel(const float* __restrict__ x, const float* __restrict__ W,
                const float* __restrict__ b, float* __restrict__ out) {
  __shared__ half2v tile[SH * SW];     // 21888 B
  __shared__ half2v wlds[NCP * 90];    //  5760 B

  const int tid = threadIdx.x;
  const int h0  = blockIdx.x * TH;   // h-tiles fastest: h-halo L2 locality
  const int w0  = blockIdx.y * TW;
  const int n   = blockIdx.z;

  // stage packed per-channel-pair weights: wlds[cp*90 + j*9 + kh*3 + kw]
  for (int s = tid; s < NCP * 90; s += 256) {
    int cp = s / 90;
    int r  = s - cp * 90;          // j*9 + kh*3 + kw
    int j  = r / 9;
    int t9 = r - j * 9;
    float wa = W[(j * 32 + 2 * cp) * 9 + t9];
    float wb = W[(j * 32 + 2 * cp + 1) * 9 + t9];
    wlds[s] = pack2(wa, wb);
  }

  const int row = tid >> 4;          // 0..15 (output row within tile)
  const int wi  = tid & 15;          // 0..15 (8-pixel chunk within tile)
  const int h   = h0 + row;
  const int wb_ = w0 + wi * 8;

  float acc[ND][8];
  #pragma unroll
  for (int d = 0; d < ND; ++d) {
    float bv = b[d];
    #pragma unroll
    for (int j = 0; j < 8; ++j) acc[d][j] = bv;
  }

  for (int cp = 0; cp < NCP; ++cp) {
    __syncthreads();   // previous iter's readers done (also covers wlds, iter 0)
    {
      const float* xa  = x + (((size_t)n * 32 + 2 * cp) * IMG) * IMG;
      const float* xbp = xa + (size_t)IMG * IMG;
      for (int s = tid; s < SH * (SW / 4); s += 256) {   // 1368 float4 slots
        int r  = s / (SW / 4);
        int q  = s - r * (SW / 4);
        int gh = h0 - HALO + r;
        int gw = w0 - PADW + 4 * q;
        float va[4] = {0.f, 0.f, 0.f, 0.f};
        float vb[4] = {0.f, 0.f, 0.f, 0.f};
        if ((unsigned)gh < (unsigned)IMG) {
          const float* pa = xa  + (size_t)gh * IMG;
          const float* pb = xbp + (size_t)gh * IMG;
          if (gw >= 0 && gw + 3 < IMG) {
            float4 t0 = *(const float4*)(pa + gw);
            float4 t1 = *(const float4*)(pb + gw);
            va[0] = t0.x; va[1] = t0.y; va[2] = t0.z; va[3] = t0.w;
            vb[0] = t1.x; vb[1] = t1.y; vb[2] = t1.z; vb[3] = t1.w;
          } else {
            #pragma unroll
            for (int i = 0; i < 4; ++i) {
              int c = gw + i;
              if ((unsigned)c < (unsigned)IMG) { va[i] = pa[c]; vb[i] = pb[c]; }
            }
          }
        }
        int rb = r * SW;
        #pragma unroll
        for (int i = 0; i < 4; ++i) {
          int wl = 4 * q + i;
          tile[rb + SWIZ(wl)] = pack2(va[i], vb[i]);
        }
      }
    }
    __syncthreads();

    const half2v* wp = &wlds[cp * 90];

    // ---- center row (kh = 1) + fused x-copy ----
    {
      const half2v* trow = &tile[(row + HALO) * SW + wi];
      half2v dk[28];                       // wloc = 8*wi + 2 + k; tap k = 10+j+kw*d
      #pragma unroll
      for (int k = 0; k < 28; ++k) dk[k] = trow[SWIZ(k + 2)];

      // copy-out: x value at (h, wb_+j) is dk[10+j]
      float* o0 = out + (((size_t)n * 42 + 2 * cp) * IMG + h) * IMG + wb_;
      float* o1 = o0 + (size_t)IMG * IMG;
      *(float4*)o0       = make_float4((float)dk[10][0], (float)dk[11][0], (float)dk[12][0], (float)dk[13][0]);
      *(float4*)(o0 + 4) = make_float4((float)dk[14][0], (float)dk[15][0], (float)dk[16][0], (float)dk[17][0]);
      *(float4*)o1       = make_float4((float)dk[10][1], (float)dk[11][1], (float)dk[12][1], (float)dk[13][1]);
      *(float4*)(o1 + 4) = make_float4((float)dk[14][1], (float)dk[15][1], (float)dk[16][1], (float)dk[17][1]);

      #pragma unroll
      for (int d = 1; d <= ND; ++d) {
        half2v wv0 = wp[(d - 1) * 9 + 3];
        half2v wv1 = wp[(d - 1) * 9 + 4];
        half2v wv2 = wp[(d - 1) * 9 + 5];
        #pragma unroll
        for (int j = 0; j < 8; ++j) {
          float a0 = acc[d - 1][j];
          a0 = dot2f(dk[10 + j - d], wv0, a0);
          a0 = dot2f(dk[10 + j],     wv1, a0);
          a0 = dot2f(dk[10 + j + d], wv2, a0);
          acc[d - 1][j] = a0;
        }
      }
    }

    // ---- side rows: row offset -d -> kh=0, +d -> kh=2 ----
    #pragma unroll
    for (int d = 1; d <= ND; ++d) {
      #pragma unroll
      for (int sgn = 0; sgn < 2; ++sgn) {
        const int tr = row + HALO + (sgn ? d : -d);
        const int kh = sgn ? 2 : 0;
        const half2v* trow = &tile[tr * SW + wi];
        half2v dk[28];
        #pragma unroll
        for (int k = 10 - d; k <= 17 + d; ++k) dk[k] = trow[SWIZ(k + 2)];
        half2v wv0 = wp[(d - 1) * 9 + kh * 3 + 0];
        half2v wv1 = wp[(d - 1) * 9 + kh * 3 + 1];
        half2v wv2 = wp[(d - 1) * 9 + kh * 3 + 2];
        #pragma unroll
        for (int j = 0; j < 8; ++j) {
          float a0 = acc[d - 1][j];
          a0 = dot2f(dk[10 + j - d], wv0, a0);
          a0 = dot2f(dk[10 + j],     wv1, a0);
          a0 = dot2f(dk[10 + j + d], wv2, a0);
          acc[d - 1][j] = a0;
        }
      }
    }
  }

  // store conv outputs (channels 32..41)
  #pragma unroll
  for (int d = 0; d < ND; ++d) {
    float* op = out + (((size_t)n * 42 + 32 + d) * IMG + h) * IMG + wb_;
    *(float4*)op       = make_float4(acc[d][0], acc[d][1], acc[d][2], acc[d][3]);
    *(float4*)(op + 4) = make_float4(acc[d][4], acc[d][5], acc[d][6], acc[d][7]);
  }
}

extern "C" void kernel_launch(void* const* d_in, const int* in_sizes, int n_in,
                              void* d_out, int out_size, void* d_ws, size_t ws_size,
                              hipStream_t stream) {
  const float* x = (const float*)d_in[0];
  const float* W = (const float*)d_in[1];
  const float* b = (const float*)d_in[2];
  float* out = (float*)d_out;
  (void)in_sizes; (void)n_in; (void)out_size; (void)d_ws; (void)ws_size;
  dim3 grid(IMG / TH, IMG / TW, 8);   // (32, 4, 8)
  dim3 block(256);
  hipLaunchKernelGGL(msd_kernel, grid, block, 0, stream, x, W, b, out);
}